// Round 8
// baseline (1025.297 us; speedup 1.0000x reference)
//
#include <hip/hip_runtime.h>
#include <math.h>

#define PLANE  9216       // 96*96
#define PLANE4 2304
#define VOL    884736     // 96^3
#define VOL4   221184
#define NC     4
#define K      7
#define HSR    3
#define SEGZ   8
#define NSEGZ  12         // 96/SEGZ

// fused y+x kernels: 192 threads = 16 rows x 12 chunks of 8 x
#define YT     16
#define YTH    22         // YT + 6 halo rows
#define TPBYX  192
#define LINW   108        // row: [4 zero pad][96][4 zero pad][4 spare]; 108%32=12
#define NF4    528        // YTH*24 float4 loads per field

__device__ __forceinline__ float4 f4zero() { return make_float4(0.f, 0.f, 0.f, 0.f); }
__device__ __forceinline__ float4 f4fma(float t, float4 a, float4 s) {
    s.x = fmaf(t, a.x, s.x); s.y = fmaf(t, a.y, s.y);
    s.z = fmaf(t, a.z, s.z); s.w = fmaf(t, a.w, s.w);
    return s;
}
__device__ __forceinline__ float4 f4fmasq(float t, float4 a, float4 s) {
    s.x = fmaf(t, a.x * a.x, s.x); s.y = fmaf(t, a.y * a.y, s.y);
    s.z = fmaf(t, a.z * a.z, s.z); s.w = fmaf(t, a.w * a.w, s.w);
    return s;
}
__device__ __forceinline__ float4 f4mul(float4 a, float4 b) {
    return make_float4(a.x * b.x, a.y * b.y, a.z * b.z, a.w * b.w);
}

// windowed y-conv for one field: 16-wide register window, then x-conv -> out[8]
__device__ __forceinline__ void conv_win(const float* __restrict__ linf,
                                         const float* __restrict__ tp,
                                         int r, int xb, float out[8])
{
    float acc[16];
#pragma unroll
    for (int i = 0; i < 16; i++) acc[i] = 0.f;
#pragma unroll
    for (int j = 0; j < K; j++) {
        const float4* lp = (const float4*)&linf[(r + j) * LINW + xb];  // = +4 + (xb-4)
        float4 w0 = lp[0], w1 = lp[1], w2 = lp[2], w3 = lp[3];
        float t = tp[j];
        acc[0]  = fmaf(t, w0.x, acc[0]);  acc[1]  = fmaf(t, w0.y, acc[1]);
        acc[2]  = fmaf(t, w0.z, acc[2]);  acc[3]  = fmaf(t, w0.w, acc[3]);
        acc[4]  = fmaf(t, w1.x, acc[4]);  acc[5]  = fmaf(t, w1.y, acc[5]);
        acc[6]  = fmaf(t, w1.z, acc[6]);  acc[7]  = fmaf(t, w1.w, acc[7]);
        acc[8]  = fmaf(t, w2.x, acc[8]);  acc[9]  = fmaf(t, w2.y, acc[9]);
        acc[10] = fmaf(t, w2.z, acc[10]); acc[11] = fmaf(t, w2.w, acc[11]);
        acc[12] = fmaf(t, w3.x, acc[12]); acc[13] = fmaf(t, w3.y, acc[13]);
        acc[14] = fmaf(t, w3.z, acc[14]); acc[15] = fmaf(t, w3.w, acc[15]);
    }
#pragma unroll
    for (int k = 0; k < 8; k++) {
        float s = 0.f;
#pragma unroll
        for (int j = 0; j < K; j++) s = fmaf(tp[j], acc[k + j + 1], s);
        out[k] = s;
    }
}

// ---------------- tables: 1D taps + boundary sums ----------------
__global__ void tables_kernel(const float* __restrict__ sigma2,
                              const float* __restrict__ sigma3,
                              float* __restrict__ taps2, float* __restrict__ taps3,
                              float* __restrict__ B2, float* __restrict__ B3)
{
    int t = threadIdx.x;
    if (t < 2 * NC) {
        int c = t % NC;
        const float* sig = (t < NC) ? sigma2 : sigma3;
        float* taps = (t < NC) ? taps2 : taps3;
        float sv = sig[c];
        float s2 = sv * sv;
        float w[K];
        float sum = 0.f;
        for (int j = 0; j < K; j++) {
            float d = (float)(j - HSR);
            w[j] = expf(-d * d / (2.f * s2));
            sum += w[j];
        }
        float inv = 1.f / sum;   // sum3d = sum^3; per-axis norm by sum reproduces it
        for (int j = 0; j < K; j++) taps[c * K + j] = w[j] * inv;
    }
    __syncthreads();
    for (int i = t; i < NC * 96; i += blockDim.x) {
        int c = i / 96, p = i % 96;
        float s2v = 0.f, s3v = 0.f;
        for (int j = 0; j < K; j++) {
            int q = p + j - HSR;
            if (q >= 0 && q < 96) { s2v += taps2[c * K + j]; s3v += taps3[c * K + j]; }
        }
        B2[i] = s2v;
        B3[i] = s3v;
    }
}

// ---------------- softmax over C (float4); reads raw arg, applies 1/eta ------
__global__ __launch_bounds__(256) void softmax_kernel(const float* __restrict__ a,
                                                      const float* __restrict__ eta,
                                                      float* __restrict__ u)
{
    int i = blockIdx.x * 256 + threadIdx.x;
    const float4* A = (const float4*)a;
    float4* U = (float4*)u;
    float inv_eta = 1.f / eta[0];
    float4 a0 = A[i], a1 = A[i + VOL4], a2 = A[i + 2 * VOL4], a3 = A[i + 3 * VOL4];
#define SM_COMP(f)                                                              \
    {                                                                           \
        float b0 = a0.f * inv_eta, b1 = a1.f * inv_eta;                         \
        float b2 = a2.f * inv_eta, b3 = a3.f * inv_eta;                         \
        float m = fmaxf(fmaxf(b0, b1), fmaxf(b2, b3));                          \
        float e0 = __expf(b0 - m), e1 = __expf(b1 - m);                         \
        float e2 = __expf(b2 - m), e3 = __expf(b3 - m);                         \
        float inv = 1.f / (e0 + e1 + e2 + e3);                                  \
        a0.f = e0 * inv; a1.f = e1 * inv; a2.f = e2 * inv; a3.f = e3 * inv;     \
    }
    SM_COMP(x) SM_COMP(y) SM_COMP(z) SM_COMP(w)
    U[i] = a0; U[i + VOL4] = a1; U[i + 2 * VOL4] = a2; U[i + 3 * VOL4] = a3;
}

// ---------------- K1: z-conv of {u*I, u (ker_lif), u (ker)}, float4 ----------
__global__ __launch_bounds__(256) void pass1_z(const float* __restrict__ u,
                                               const float* __restrict__ I,
                                               const float* __restrict__ taps2,
                                               const float* __restrict__ taps3,
                                               float* __restrict__ a0, float* __restrict__ a1,
                                               float* __restrict__ a2)
{
    int p4 = blockIdx.x * 256 + threadIdx.x;   // float4 index within plane
    int s  = blockIdx.y;
    int c  = blockIdx.z;
    int z0 = s * SEGZ;
    const float4* ub = (const float4*)(u + (size_t)c * VOL) + p4;
    const float4* Ib = (const float4*)I + p4;
    float t3[K], t2[K];
#pragma unroll
    for (int j = 0; j < K; j++) { t3[j] = taps3[c * K + j]; t2[j] = taps2[c * K + j]; }
    float4 wu[K], wui[K];
#pragma unroll
    for (int j = 0; j < K - 1; j++) {
        int z = z0 + j - HSR;
        float4 uv = f4zero(), iv = f4zero();
        if (z >= 0 && z < 96) { uv = ub[z * PLANE4]; iv = Ib[z * PLANE4]; }
        wu[j] = uv; wui[j] = f4mul(uv, iv);
    }
    float4* o0 = (float4*)(a0 + (size_t)c * VOL) + p4;
    float4* o1 = (float4*)(a1 + (size_t)c * VOL) + p4;
    float4* o2 = (float4*)(a2 + (size_t)c * VOL) + p4;
    for (int k = 0; k < SEGZ; k++) {
        int z = z0 + k, zl = z + HSR;
        float4 uv = f4zero(), iv = f4zero();
        if (zl < 96) { uv = ub[zl * PLANE4]; iv = Ib[zl * PLANE4]; }
        wu[K - 1] = uv; wui[K - 1] = f4mul(uv, iv);
        float4 s0 = f4zero(), s1 = f4zero(), s2 = f4zero();
#pragma unroll
        for (int j = 0; j < K; j++) {
            s0 = f4fma(t3[j], wui[j], s0);
            s1 = f4fma(t3[j], wu[j], s1);
            s2 = f4fma(t2[j], wu[j], s2);
        }
        o0[z * PLANE4] = s0;
        o1[z * PLANE4] = s1;
        o2[z * PLANE4] = s2;
#pragma unroll
        for (int j = 0; j < K - 1; j++) { wu[j] = wu[j + 1]; wui[j] = wui[j + 1]; }
    }
}

// ---------------- K2: y+x conv of 2 fields -> Cn. 1 barrier, no mid ---------
// LDS 19 KB -> 8 blocks/CU (24 waves).
__global__ __launch_bounds__(TPBYX) void pass2_yx(const float* __restrict__ a0,
                                                  const float* __restrict__ a1,
                                                  const float* __restrict__ taps3,
                                                  float* __restrict__ Cn)
{
    __shared__ float lin[2][YTH * LINW];
    int yt = blockIdx.x, z = blockIdx.y, c = blockIdx.z;
    int y0 = yt * YT, tid = threadIdx.x;
    size_t base = (size_t)c * VOL + (size_t)z * PLANE;
    {
        const float4* g0 = (const float4*)(a0 + base);
        const float4* g1 = (const float4*)(a1 + base);
#pragma unroll
        for (int i4 = tid; i4 < NF4; i4 += TPBYX) {
            int r = i4 / 24, k = i4 - r * 24;
            int gy = y0 - HSR + r;
            bool ok = (gy >= 0 && gy < 96);
            int gi = gy * 24 + k;
            float4 v0 = ok ? g0[gi] : f4zero();
            float4 v1 = ok ? g1[gi] : f4zero();
            int li = r * LINW + 4 + k * 4;
            *(float4*)&lin[0][li] = v0;
            *(float4*)&lin[1][li] = v1;
        }
    }
    if (tid < YTH * 8) {   // zero the x pads
        int r = tid >> 3, p = tid & 7;
        int idx = r * LINW + (p < 4 ? p : 96 + p);
        lin[0][idx] = 0.f; lin[1][idx] = 0.f;
    }
    float t3[K];
#pragma unroll
    for (int j = 0; j < K; j++) t3[j] = taps3[c * K + j];
    __syncthreads();
    int r  = tid / 12;
    int xb = (tid - r * 12) * 8;
    float outA[8], outB[8];
    conv_win(lin[0], t3, r, xb, outA);
    conv_win(lin[1], t3, r, xb, outB);
    int y = y0 + r;
    float co[8];
#pragma unroll
    for (int k = 0; k < 8; k++)
        co[k] = (outA[k] + 1e-6f) / (outB[k] + 1e-6f);
    float* cp = Cn + base + y * 96 + xb;
    *(float4*)cp       = *(float4*)&co[0];
    *(float4*)(cp + 4) = *(float4*)&co[4];
}

// ---------------- K3: z-conv of {Cn, Cn^2}, float4, 256t ----------------
__global__ __launch_bounds__(256) void pass4_z(const float* __restrict__ Cn,
                                               const float* __restrict__ taps3,
                                               float* __restrict__ b0, float* __restrict__ b1)
{
    int p4 = blockIdx.x * 256 + threadIdx.x;
    int s  = blockIdx.y;
    int c  = blockIdx.z;
    int z0 = s * SEGZ;
    const float4* ib = (const float4*)(Cn + (size_t)c * VOL) + p4;
    float t3[K];
#pragma unroll
    for (int j = 0; j < K; j++) t3[j] = taps3[c * K + j];
    float4 w[K];
#pragma unroll
    for (int j = 0; j < K - 1; j++) {
        int z = z0 + j - HSR;
        float4 v = f4zero();
        if (z >= 0 && z < 96) v = ib[z * PLANE4];
        w[j] = v;
    }
    float4* o0 = (float4*)(b0 + (size_t)c * VOL) + p4;
    float4* o1 = (float4*)(b1 + (size_t)c * VOL) + p4;
    for (int k = 0; k < SEGZ; k++) {
        int z = z0 + k, zl = z + HSR;
        float4 v = f4zero();
        if (zl < 96) v = ib[zl * PLANE4];
        w[K - 1] = v;
        float4 s0 = f4zero(), s1 = f4zero();
#pragma unroll
        for (int j = 0; j < K; j++) {
            s0 = f4fma(t3[j], w[j], s0);
            s1 = f4fmasq(t3[j], w[j], s1);
        }
        o0[z * PLANE4] = s0;
        o1[z * PLANE4] = s1;
#pragma unroll
        for (int j = 0; j < K - 1; j++) w[j] = w[j + 1];
    }
}

// ---------------- K4: y+x conv of {cz0(t3), cz1(t3), a2(t2)} + Lif + q + arg --
// 1 barrier, no mid. LDS 28.5 KB -> 5 blocks/CU (15 waves).
__global__ __launch_bounds__(TPBYX) void pass5_yx(const float* __restrict__ cz0,
                                                  const float* __restrict__ cz1,
                                                  const float* __restrict__ a2,
                                                  const float* __restrict__ o,
                                                  const float* __restrict__ I,
                                                  const float* __restrict__ taps2,
                                                  const float* __restrict__ taps3,
                                                  const float* __restrict__ B2,
                                                  const float* __restrict__ B3,
                                                  const float* __restrict__ lam,
                                                  const float* __restrict__ mu,
                                                  float* __restrict__ argb)
{
    __shared__ float lin[3][YTH * LINW];
    int yt = blockIdx.x, z = blockIdx.y, c = blockIdx.z;
    int y0 = yt * YT, tid = threadIdx.x;
    size_t base = (size_t)c * VOL + (size_t)z * PLANE;
    {
        const float4* g0 = (const float4*)(cz0 + base);
        const float4* g1 = (const float4*)(cz1 + base);
        const float4* g2 = (const float4*)(a2 + base);
#pragma unroll
        for (int i4 = tid; i4 < NF4; i4 += TPBYX) {
            int r = i4 / 24, k = i4 - r * 24;
            int gy = y0 - HSR + r;
            bool ok = (gy >= 0 && gy < 96);
            int gi = gy * 24 + k;
            float4 v0 = ok ? g0[gi] : f4zero();
            float4 v1 = ok ? g1[gi] : f4zero();
            float4 v2 = ok ? g2[gi] : f4zero();
            int li = r * LINW + 4 + k * 4;
            *(float4*)&lin[0][li] = v0;
            *(float4*)&lin[1][li] = v1;
            *(float4*)&lin[2][li] = v2;
        }
    }
    if (tid < YTH * 8) {
        int r = tid >> 3, p = tid & 7;
        int idx = r * LINW + (p < 4 ? p : 96 + p);
        lin[0][idx] = 0.f; lin[1][idx] = 0.f; lin[2][idx] = 0.f;
    }
    float t3[K], t2[K];
#pragma unroll
    for (int j = 0; j < K; j++) { t3[j] = taps3[c * K + j]; t2[j] = taps2[c * K + j]; }
    __syncthreads();
    int r  = tid / 12;
    int xb = (tid - r * 12) * 8;
    float d0[8], d1[8], s2[8];
    conv_win(lin[0], t3, r, xb, d0);
    conv_win(lin[1], t3, r, xb, d1);
    conv_win(lin[2], t2, r, xb, s2);
    int y = y0 + r;
    int v = z * PLANE + y * 96 + xb;
    float lamv = lam[0], muv = mu[0];
    float Bz3 = B3[c * 96 + z], By3 = B3[c * 96 + y];
    float Bz2 = B2[c * 96 + z], By2 = B2[c * 96 + y];
    float Bx3[8], Bx2[8], Ivv[8], ov[8];
    {
        const float4* bx3 = (const float4*)&B3[c * 96 + xb];
        *(float4*)&Bx3[0] = bx3[0]; *(float4*)&Bx3[4] = bx3[1];
        const float4* bx2 = (const float4*)&B2[c * 96 + xb];
        *(float4*)&Bx2[0] = bx2[0]; *(float4*)&Bx2[4] = bx2[1];
        const float4* ip = (const float4*)&I[v];
        *(float4*)&Ivv[0] = ip[0]; *(float4*)&Ivv[4] = ip[1];
        const float4* op = (const float4*)&o[(size_t)c * VOL + v];
        *(float4*)&ov[0] = op[0]; *(float4*)&ov[4] = op[1];
    }
    float res[8];
#pragma unroll
    for (int k = 0; k < 8; k++) {
        float Iv = Ivv[k];
        float cones = Bz3 * By3 * Bx3[k];
        float Lif = d1[k] - 2.f * Iv * d0[k] + Iv * Iv * cones;
        float qv  = fmaf(Bz2 * By2, Bx2[k], -2.f * s2[k]);
        res[k] = ov[k] - muv * Lif - lamv * qv;   // unscaled; softmax applies 1/eta
    }
    float* ap = argb + base + y * 96 + xb;
    *(float4*)ap       = *(float4*)&res[0];
    *(float4*)(ap + 4) = *(float4*)&res[4];
}

extern "C" void kernel_launch(void* const* d_in, const int* in_sizes, int n_in,
                              void* d_out, int out_size, void* d_ws, size_t ws_size,
                              hipStream_t stream)
{
    const float* o      = (const float*)d_in[0];
    const float* I      = (const float*)d_in[1];
    const float* sigma2 = (const float*)d_in[2];
    const float* sigma3 = (const float*)d_in[3];
    const float* eta    = (const float*)d_in[4];
    const float* lam    = (const float*)d_in[5];
    const float* mu     = (const float*)d_in[6];
    float* u = (float*)d_out;

    float* wsf = (float*)d_ws;
    float* taps2 = wsf;              // 28 floats
    float* taps3 = wsf + 32;
    float* B2    = wsf + 64;         // 384 floats
    float* B3    = wsf + 64 + NC * 96;
    float* buf   = wsf + 1024;
    const size_t VCs = (size_t)NC * VOL;
    float* a0 = buf;                 // z-conv outs; a0 reused as arg buffer
    float* a1 = buf + VCs;
    float* a2 = buf + 2 * VCs;
    float* Cn = buf + 3 * VCs;
    float* c0 = buf + 4 * VCs;       // z-conv of Cn, Cn^2
    float* c1 = buf + 5 * VCs;

    const dim3 gridZ(PLANE4 / 256, NSEGZ, NC);  // 9 x 12 x 4 = 432 blocks (256t)
    const dim3 gridYX(96 / YT, 96, NC);         // 6 x 96 x 4 = 2304 blocks (192t)
    const int gridV4 = VOL4 / 256;              // 864

    tables_kernel<<<1, 512, 0, stream>>>(sigma2, sigma3, taps2, taps3, B2, B3);
    softmax_kernel<<<gridV4, 256, 0, stream>>>(o, eta, u);   // u0 = softmax(o/eta)
    for (int it = 0; it < 10; it++) {
        pass1_z<<<gridZ, 256, 0, stream>>>(u, I, taps2, taps3, a0, a1, a2);
        pass2_yx<<<gridYX, TPBYX, 0, stream>>>(a0, a1, taps3, Cn);
        pass4_z<<<gridZ, 256, 0, stream>>>(Cn, taps3, c0, c1);
        pass5_yx<<<gridYX, TPBYX, 0, stream>>>(c0, c1, a2, o, I, taps2, taps3,
                                               B2, B3, lam, mu, a0);
        softmax_kernel<<<gridV4, 256, 0, stream>>>(a0, eta, u);
    }
}

// Round 9
// 682.734 us; speedup vs baseline: 1.5018x; 1.5018x over previous
//
#include <hip/hip_runtime.h>
#include <hip/hip_fp16.h>
#include <math.h>

#define PLANE  9216       // 96*96
#define PLANE4 2304
#define VOL    884736     // 96^3
#define VOL4   221184
#define NC     4
#define K      7
#define HSR    3
#define SEGZ   8
#define NSEGZ  12         // 96/SEGZ

// fused y+x kernels: 192 threads = 16 rows x 12 chunks of 8 x
#define YT     16
#define YTH    22         // YT + 6 halo rows
#define TPBYX  192
#define LINW   100        // lin row stride (dwords); breaks bank aliasing
#define MIDW   108        // mid row stride: 4 pad + 96 + 4 pad (+4 spare)
#define NF4    528        // YTH*24 4-value chunks per field

__device__ __forceinline__ float4 f4zero() { return make_float4(0.f, 0.f, 0.f, 0.f); }
__device__ __forceinline__ float4 f4fma(float t, float4 a, float4 s) {
    s.x = fmaf(t, a.x, s.x); s.y = fmaf(t, a.y, s.y);
    s.z = fmaf(t, a.z, s.z); s.w = fmaf(t, a.w, s.w);
    return s;
}
__device__ __forceinline__ float4 f4fmasq(float t, float4 a, float4 s) {
    s.x = fmaf(t, a.x * a.x, s.x); s.y = fmaf(t, a.y * a.y, s.y);
    s.z = fmaf(t, a.z * a.z, s.z); s.w = fmaf(t, a.w * a.w, s.w);
    return s;
}
__device__ __forceinline__ float4 f4mul(float4 a, float4 b) {
    return make_float4(a.x * b.x, a.y * b.y, a.z * b.z, a.w * b.w);
}
// fp16 pack/unpack (storage-only fp16; all math fp32)
__device__ __forceinline__ float4 h4tof4(ushort4 s) {
    return make_float4(__half2float(__ushort_as_half(s.x)),
                       __half2float(__ushort_as_half(s.y)),
                       __half2float(__ushort_as_half(s.z)),
                       __half2float(__ushort_as_half(s.w)));
}
__device__ __forceinline__ ushort4 f4toh4(float4 v) {
    ushort4 s;
    s.x = __half_as_ushort(__float2half_rn(v.x));
    s.y = __half_as_ushort(__float2half_rn(v.y));
    s.z = __half_as_ushort(__float2half_rn(v.z));
    s.w = __half_as_ushort(__float2half_rn(v.w));
    return s;
}

// ---------------- tables: 1D taps + boundary sums ----------------
__global__ void tables_kernel(const float* __restrict__ sigma2,
                              const float* __restrict__ sigma3,
                              float* __restrict__ taps2, float* __restrict__ taps3,
                              float* __restrict__ B2, float* __restrict__ B3)
{
    int t = threadIdx.x;
    if (t < 2 * NC) {
        int c = t % NC;
        const float* sig = (t < NC) ? sigma2 : sigma3;
        float* taps = (t < NC) ? taps2 : taps3;
        float sv = sig[c];
        float s2 = sv * sv;
        float w[K];
        float sum = 0.f;
        for (int j = 0; j < K; j++) {
            float d = (float)(j - HSR);
            w[j] = expf(-d * d / (2.f * s2));
            sum += w[j];
        }
        float inv = 1.f / sum;   // sum3d = sum^3; per-axis norm by sum reproduces it
        for (int j = 0; j < K; j++) taps[c * K + j] = w[j] * inv;
    }
    __syncthreads();
    for (int i = t; i < NC * 96; i += blockDim.x) {
        int c = i / 96, p = i % 96;
        float s2v = 0.f, s3v = 0.f;
        for (int j = 0; j < K; j++) {
            int q = p + j - HSR;
            if (q >= 0 && q < 96) { s2v += taps2[c * K + j]; s3v += taps3[c * K + j]; }
        }
        B2[i] = s2v;
        B3[i] = s3v;
    }
}

// ---------------- softmax over C (float4); applies 1/eta ------
__global__ __launch_bounds__(256) void softmax_kernel(const float* __restrict__ a,
                                                      const float* __restrict__ eta,
                                                      float* __restrict__ u)
{
    int i = blockIdx.x * 256 + threadIdx.x;
    const float4* A = (const float4*)a;
    float4* U = (float4*)u;
    float inv_eta = 1.f / eta[0];
    float4 a0 = A[i], a1 = A[i + VOL4], a2 = A[i + 2 * VOL4], a3 = A[i + 3 * VOL4];
#define SM_COMP(f)                                                              \
    {                                                                           \
        float b0 = a0.f * inv_eta, b1 = a1.f * inv_eta;                         \
        float b2 = a2.f * inv_eta, b3 = a3.f * inv_eta;                         \
        float m = fmaxf(fmaxf(b0, b1), fmaxf(b2, b3));                          \
        float e0 = __expf(b0 - m), e1 = __expf(b1 - m);                         \
        float e2 = __expf(b2 - m), e3 = __expf(b3 - m);                         \
        float inv = 1.f / (e0 + e1 + e2 + e3);                                  \
        a0.f = e0 * inv; a1.f = e1 * inv; a2.f = e2 * inv; a3.f = e3 * inv;     \
    }
    SM_COMP(x) SM_COMP(y) SM_COMP(z) SM_COMP(w)
    U[i] = a0; U[i + VOL4] = a1; U[i + 2 * VOL4] = a2; U[i + 3 * VOL4] = a3;
}

// ---------------- K1: z-conv of {u*I, u (ker_lif), u (ker)} -> fp16 outs -----
__global__ __launch_bounds__(256) void pass1_z(const float* __restrict__ u,
                                               const float* __restrict__ I,
                                               const float* __restrict__ taps2,
                                               const float* __restrict__ taps3,
                                               __half* __restrict__ a0, __half* __restrict__ a1,
                                               __half* __restrict__ a2)
{
    int p4 = blockIdx.x * 256 + threadIdx.x;   // 4-value index within plane
    int s  = blockIdx.y;
    int c  = blockIdx.z;
    int z0 = s * SEGZ;
    const float4* ub = (const float4*)(u + (size_t)c * VOL) + p4;
    const float4* Ib = (const float4*)I + p4;
    float t3[K], t2[K];
#pragma unroll
    for (int j = 0; j < K; j++) { t3[j] = taps3[c * K + j]; t2[j] = taps2[c * K + j]; }
    float4 wu[K], wui[K];
#pragma unroll
    for (int j = 0; j < K - 1; j++) {
        int z = z0 + j - HSR;
        float4 uv = f4zero(), iv = f4zero();
        if (z >= 0 && z < 96) { uv = ub[z * PLANE4]; iv = Ib[z * PLANE4]; }
        wu[j] = uv; wui[j] = f4mul(uv, iv);
    }
    ushort4* o0 = (ushort4*)(a0 + (size_t)c * VOL) + p4;
    ushort4* o1 = (ushort4*)(a1 + (size_t)c * VOL) + p4;
    ushort4* o2 = (ushort4*)(a2 + (size_t)c * VOL) + p4;
    for (int k = 0; k < SEGZ; k++) {
        int z = z0 + k, zl = z + HSR;
        float4 uv = f4zero(), iv = f4zero();
        if (zl < 96) { uv = ub[zl * PLANE4]; iv = Ib[zl * PLANE4]; }
        wu[K - 1] = uv; wui[K - 1] = f4mul(uv, iv);
        float4 s0 = f4zero(), s1 = f4zero(), s2 = f4zero();
#pragma unroll
        for (int j = 0; j < K; j++) {
            s0 = f4fma(t3[j], wui[j], s0);
            s1 = f4fma(t3[j], wu[j], s1);
            s2 = f4fma(t2[j], wu[j], s2);
        }
        o0[z * PLANE4] = f4toh4(s0);
        o1[z * PLANE4] = f4toh4(s1);
        o2[z * PLANE4] = f4toh4(s2);
#pragma unroll
        for (int j = 0; j < K - 1; j++) { wu[j] = wu[j + 1]; wui[j] = wui[j + 1]; }
    }
}

// ---------------- K2: fused y+x conv of 3 fp16 fields -> Cn, q (fp16) --------
// 192t, b128 LDS (fp32 lin/mid), mids in registers, 2 barriers. LDS 47 KB.
__global__ __launch_bounds__(TPBYX) void pass2_yx(const __half* __restrict__ a0,
                                                  const __half* __restrict__ a1,
                                                  const __half* __restrict__ a2,
                                                  const float* __restrict__ taps2,
                                                  const float* __restrict__ taps3,
                                                  const float* __restrict__ B2,
                                                  __half* __restrict__ Cn,
                                                  __half* __restrict__ q)
{
    __shared__ float lin[3][YTH * LINW];
    __shared__ float mid[3][YT * MIDW];
    int yt = blockIdx.x, z = blockIdx.y, c = blockIdx.z;
    int y0 = yt * YT, tid = threadIdx.x;
    size_t base = (size_t)c * VOL + (size_t)z * PLANE;
    {
        const ushort4* g0 = (const ushort4*)(a0 + base);
        const ushort4* g1 = (const ushort4*)(a1 + base);
        const ushort4* g2 = (const ushort4*)(a2 + base);
#pragma unroll
        for (int i4 = tid; i4 < NF4; i4 += TPBYX) {
            int r = i4 / 24, k = i4 - r * 24;
            int gy = y0 - HSR + r;
            bool ok = (gy >= 0 && gy < 96);
            int gi = gy * 24 + k;
            float4 v0 = ok ? h4tof4(g0[gi]) : f4zero();
            float4 v1 = ok ? h4tof4(g1[gi]) : f4zero();
            float4 v2 = ok ? h4tof4(g2[gi]) : f4zero();
            int li = r * LINW + k * 4;
            *(float4*)&lin[0][li] = v0;
            *(float4*)&lin[1][li] = v1;
            *(float4*)&lin[2][li] = v2;
        }
    }
    if (tid < 128) {   // zero mid x-pads
        int r = tid >> 3, p = tid & 7;
        int idx = r * MIDW + (p < 4 ? p : 96 + p);
        mid[0][idx] = 0.f; mid[1][idx] = 0.f; mid[2][idx] = 0.f;
    }
    float t3[K], t2[K];
#pragma unroll
    for (int j = 0; j < K; j++) { t3[j] = taps3[c * K + j]; t2[j] = taps2[c * K + j]; }
    __syncthreads();
    int r  = tid / 12;
    int xb = (tid - r * 12) * 8;
#pragma unroll
    for (int f = 0; f < 3; f++) {
        const float* tp = (f < 2) ? t3 : t2;
        float4 mA = f4zero(), mB = f4zero();
#pragma unroll
        for (int j = 0; j < K; j++) {
            const float4* lp = (const float4*)&lin[f][(r + j) * LINW + xb];
            mA = f4fma(tp[j], lp[0], mA);
            mB = f4fma(tp[j], lp[1], mB);
        }
        float4* mp = (float4*)&mid[f][r * MIDW + 4 + xb];
        mp[0] = mA; mp[1] = mB;
    }
    __syncthreads();
    float outA[8], outB[8], outC[8];
    {
        float wf[16];
#pragma unroll
        for (int f = 0; f < 3; f++) {
            const float* tp = (f < 2) ? t3 : t2;
            const float4* wp = (const float4*)&mid[f][r * MIDW + xb];
            *(float4*)&wf[0]  = wp[0];
            *(float4*)&wf[4]  = wp[1];
            *(float4*)&wf[8]  = wp[2];
            *(float4*)&wf[12] = wp[3];
            float* dst = (f == 0) ? outA : (f == 1) ? outB : outC;
#pragma unroll
            for (int k = 0; k < 8; k++) {
                float s = 0.f;
#pragma unroll
                for (int j = 0; j < K; j++) s = fmaf(tp[j], wf[k + j + 1], s);
                dst[k] = s;
            }
        }
    }
    int y = y0 + r;
    float Bz = B2[c * 96 + z];
    float By = B2[c * 96 + y];
    float Bx[8];
    {
        const float4* bx = (const float4*)&B2[c * 96 + xb];
        *(float4*)&Bx[0] = bx[0];
        *(float4*)&Bx[4] = bx[1];
    }
    float co[8], qo[8];
#pragma unroll
    for (int k = 0; k < 8; k++) {
        co[k] = (outA[k] + 1e-6f) / (outB[k] + 1e-6f);
        qo[k] = fmaf(Bz * By, Bx[k], -2.f * outC[k]);
    }
    ushort4* cp = (ushort4*)(Cn + base + y * 96 + xb);
    ushort4* qp = (ushort4*)(q  + base + y * 96 + xb);
    cp[0] = f4toh4(*(float4*)&co[0]);
    cp[1] = f4toh4(*(float4*)&co[4]);
    qp[0] = f4toh4(*(float4*)&qo[0]);
    qp[1] = f4toh4(*(float4*)&qo[4]);
}

// ---------------- K3: z-conv of {Cn, Cn^2}, fp16 in/out ----------------
__global__ __launch_bounds__(256) void pass4_z(const __half* __restrict__ Cn,
                                               const float* __restrict__ taps3,
                                               __half* __restrict__ b0, __half* __restrict__ b1)
{
    int p4 = blockIdx.x * 256 + threadIdx.x;
    int s  = blockIdx.y;
    int c  = blockIdx.z;
    int z0 = s * SEGZ;
    const ushort4* ib = (const ushort4*)(Cn + (size_t)c * VOL) + p4;
    float t3[K];
#pragma unroll
    for (int j = 0; j < K; j++) t3[j] = taps3[c * K + j];
    float4 w[K];
#pragma unroll
    for (int j = 0; j < K - 1; j++) {
        int z = z0 + j - HSR;
        float4 v = f4zero();
        if (z >= 0 && z < 96) v = h4tof4(ib[z * PLANE4]);
        w[j] = v;
    }
    ushort4* o0 = (ushort4*)(b0 + (size_t)c * VOL) + p4;
    ushort4* o1 = (ushort4*)(b1 + (size_t)c * VOL) + p4;
    for (int k = 0; k < SEGZ; k++) {
        int z = z0 + k, zl = z + HSR;
        float4 v = f4zero();
        if (zl < 96) v = h4tof4(ib[zl * PLANE4]);
        w[K - 1] = v;
        float4 s0 = f4zero(), s1 = f4zero();
#pragma unroll
        for (int j = 0; j < K; j++) {
            s0 = f4fma(t3[j], w[j], s0);
            s1 = f4fmasq(t3[j], w[j], s1);
        }
        o0[z * PLANE4] = f4toh4(s0);
        o1[z * PLANE4] = f4toh4(s1);
#pragma unroll
        for (int j = 0; j < K - 1; j++) w[j] = w[j + 1];
    }
}

// ---------------- K4: fused y+x conv of {c0,c1} (fp16) + Lif + arg (fp32) ----
// LDS 31.4 KB -> 5 blocks/CU.
__global__ __launch_bounds__(TPBYX) void pass5_yx(const __half* __restrict__ cz0,
                                                  const __half* __restrict__ cz1,
                                                  const __half* __restrict__ q,
                                                  const float* __restrict__ o,
                                                  const float* __restrict__ I,
                                                  const float* __restrict__ taps3,
                                                  const float* __restrict__ B3,
                                                  const float* __restrict__ lam,
                                                  const float* __restrict__ mu,
                                                  float* __restrict__ argb)
{
    __shared__ float lin[2][YTH * LINW];
    __shared__ float mid[2][YT * MIDW];
    int yt = blockIdx.x, z = blockIdx.y, c = blockIdx.z;
    int y0 = yt * YT, tid = threadIdx.x;
    size_t base = (size_t)c * VOL + (size_t)z * PLANE;
    {
        const ushort4* g0 = (const ushort4*)(cz0 + base);
        const ushort4* g1 = (const ushort4*)(cz1 + base);
#pragma unroll
        for (int i4 = tid; i4 < NF4; i4 += TPBYX) {
            int r = i4 / 24, k = i4 - r * 24;
            int gy = y0 - HSR + r;
            bool ok = (gy >= 0 && gy < 96);
            int gi = gy * 24 + k;
            float4 v0 = ok ? h4tof4(g0[gi]) : f4zero();
            float4 v1 = ok ? h4tof4(g1[gi]) : f4zero();
            int li = r * LINW + k * 4;
            *(float4*)&lin[0][li] = v0;
            *(float4*)&lin[1][li] = v1;
        }
    }
    if (tid < 128) {
        int r = tid >> 3, p = tid & 7;
        int idx = r * MIDW + (p < 4 ? p : 96 + p);
        mid[0][idx] = 0.f; mid[1][idx] = 0.f;
    }
    float t3[K];
#pragma unroll
    for (int j = 0; j < K; j++) t3[j] = taps3[c * K + j];
    __syncthreads();
    int r  = tid / 12;
    int xb = (tid - r * 12) * 8;
#pragma unroll
    for (int f = 0; f < 2; f++) {
        float4 mA = f4zero(), mB = f4zero();
#pragma unroll
        for (int j = 0; j < K; j++) {
            const float4* lp = (const float4*)&lin[f][(r + j) * LINW + xb];
            mA = f4fma(t3[j], lp[0], mA);
            mB = f4fma(t3[j], lp[1], mB);
        }
        float4* mp = (float4*)&mid[f][r * MIDW + 4 + xb];
        mp[0] = mA; mp[1] = mB;
    }
    __syncthreads();
    float d0[8], d1[8];
    {
        float wf[16];
#pragma unroll
        for (int f = 0; f < 2; f++) {
            const float4* wp = (const float4*)&mid[f][r * MIDW + xb];
            *(float4*)&wf[0]  = wp[0];
            *(float4*)&wf[4]  = wp[1];
            *(float4*)&wf[8]  = wp[2];
            *(float4*)&wf[12] = wp[3];
            float* dst = (f == 0) ? d0 : d1;
#pragma unroll
            for (int k = 0; k < 8; k++) {
                float s = 0.f;
#pragma unroll
                for (int j = 0; j < K; j++) s = fmaf(t3[j], wf[k + j + 1], s);
                dst[k] = s;
            }
        }
    }
    int y = y0 + r;
    int v = z * PLANE + y * 96 + xb;
    float lamv = lam[0], muv = mu[0];
    float Bz = B3[c * 96 + z];
    float By = B3[c * 96 + y];
    float Bx[8], Ivv[8], ov[8], qv[8];
    {
        const float4* bx = (const float4*)&B3[c * 96 + xb];
        *(float4*)&Bx[0] = bx[0]; *(float4*)&Bx[4] = bx[1];
        const float4* ip = (const float4*)&I[v];
        *(float4*)&Ivv[0] = ip[0]; *(float4*)&Ivv[4] = ip[1];
        const float4* op = (const float4*)&o[(size_t)c * VOL + v];
        *(float4*)&ov[0] = op[0]; *(float4*)&ov[4] = op[1];
        const ushort4* qp = (const ushort4*)(q + (size_t)c * VOL + v);
        *(float4*)&qv[0] = h4tof4(qp[0]);
        *(float4*)&qv[4] = h4tof4(qp[1]);
    }
    float res[8];
#pragma unroll
    for (int k = 0; k < 8; k++) {
        float Iv = Ivv[k];
        float cones = Bz * By * Bx[k];
        float Lif = d1[k] - 2.f * Iv * d0[k] + Iv * Iv * cones;
        res[k] = ov[k] - muv * Lif - lamv * qv[k];   // unscaled; softmax applies 1/eta
    }
    float* ap = argb + base + y * 96 + xb;
    *(float4*)ap       = *(float4*)&res[0];
    *(float4*)(ap + 4) = *(float4*)&res[4];
}

extern "C" void kernel_launch(void* const* d_in, const int* in_sizes, int n_in,
                              void* d_out, int out_size, void* d_ws, size_t ws_size,
                              hipStream_t stream)
{
    const float* o      = (const float*)d_in[0];
    const float* I      = (const float*)d_in[1];
    const float* sigma2 = (const float*)d_in[2];
    const float* sigma3 = (const float*)d_in[3];
    const float* eta    = (const float*)d_in[4];
    const float* lam    = (const float*)d_in[5];
    const float* mu     = (const float*)d_in[6];
    float* u = (float*)d_out;

    float* wsf = (float*)d_ws;
    float* taps2 = wsf;              // 28 floats
    float* taps3 = wsf + 32;
    float* B2    = wsf + 64;         // 384 floats
    float* B3    = wsf + 64 + NC * 96;
    const size_t VCs = (size_t)NC * VOL;
    float* argb  = wsf + 1024;       // fp32 arg buffer (4*VOL floats)
    __half* hbuf = (__half*)(wsf + 1024 + VCs);
    __half* a0 = hbuf;               // z-conv outs (fp16)
    __half* a1 = hbuf + VCs;
    __half* a2 = hbuf + 2 * VCs;
    __half* Cn = hbuf + 3 * VCs;
    __half* qb = hbuf + 4 * VCs;
    __half* c0 = hbuf + 5 * VCs;     // z-conv of Cn, Cn^2 (fp16)
    __half* c1 = hbuf + 6 * VCs;

    const dim3 gridZ(PLANE4 / 256, NSEGZ, NC);  // 9 x 12 x 4 = 432 blocks (256t)
    const dim3 gridYX(96 / YT, 96, NC);         // 6 x 96 x 4 = 2304 blocks (192t)
    const int gridV4 = VOL4 / 256;              // 864

    tables_kernel<<<1, 512, 0, stream>>>(sigma2, sigma3, taps2, taps3, B2, B3);
    softmax_kernel<<<gridV4, 256, 0, stream>>>(o, eta, u);   // u0 = softmax(o/eta)
    for (int it = 0; it < 10; it++) {
        pass1_z<<<gridZ, 256, 0, stream>>>(u, I, taps2, taps3, a0, a1, a2);
        pass2_yx<<<gridYX, TPBYX, 0, stream>>>(a0, a1, a2, taps2, taps3, B2, Cn, qb);
        pass4_z<<<gridZ, 256, 0, stream>>>(Cn, taps3, c0, c1);
        pass5_yx<<<gridYX, TPBYX, 0, stream>>>(c0, c1, qb, o, I, taps3, B3,
                                               lam, mu, argb);
        softmax_kernel<<<gridV4, 256, 0, stream>>>(argb, eta, u);
    }
}

// Round 10
// 664.150 us; speedup vs baseline: 1.5438x; 1.0280x over previous
//
#include <hip/hip_runtime.h>
#include <hip/hip_fp16.h>
#include <math.h>

#define PLANE  9216       // 96*96
#define PLANE4 2304
#define VOL    884736     // 96^3
#define VOL4   221184
#define NC     4
#define K      7
#define HSR    3
#define SEGZ   8
#define NSEGZ  12         // 96/SEGZ

// fused y+x kernels: 192 threads = 16 rows x 12 chunks of 8 x
#define YT     16
#define YTH    22         // YT + 6 halo rows
#define TPBYX  192
#define LINWH  112        // fp16 lin row: [8 pad][96][8 pad] halves; keeps b128 reads 16B-aligned
#define MIDW   108        // fp32 mid row stride: 4 pad + 96 + 4 pad (+4 spare)
#define NF4    528        // YTH*24 ushort4 chunks per field

__device__ __forceinline__ float4 f4zero() { return make_float4(0.f, 0.f, 0.f, 0.f); }
__device__ __forceinline__ float4 f4fma(float t, float4 a, float4 s) {
    s.x = fmaf(t, a.x, s.x); s.y = fmaf(t, a.y, s.y);
    s.z = fmaf(t, a.z, s.z); s.w = fmaf(t, a.w, s.w);
    return s;
}
__device__ __forceinline__ float4 f4fmasq(float t, float4 a, float4 s) {
    s.x = fmaf(t, a.x * a.x, s.x); s.y = fmaf(t, a.y * a.y, s.y);
    s.z = fmaf(t, a.z * a.z, s.z); s.w = fmaf(t, a.w * a.w, s.w);
    return s;
}
__device__ __forceinline__ float4 f4mul(float4 a, float4 b) {
    return make_float4(a.x * b.x, a.y * b.y, a.z * b.z, a.w * b.w);
}
// fp16 pack/unpack (storage-only fp16; all math fp32)
__device__ __forceinline__ float4 h4tof4(ushort4 s) {
    return make_float4(__half2float(__ushort_as_half(s.x)),
                       __half2float(__ushort_as_half(s.y)),
                       __half2float(__ushort_as_half(s.z)),
                       __half2float(__ushort_as_half(s.w)));
}
__device__ __forceinline__ ushort4 f4toh4(float4 v) {
    ushort4 s;
    s.x = __half_as_ushort(__float2half_rn(v.x));
    s.y = __half_as_ushort(__float2half_rn(v.y));
    s.z = __half_as_ushort(__float2half_rn(v.z));
    s.w = __half_as_ushort(__float2half_rn(v.w));
    return s;
}
// y-conv accumulate: 8 halves from one b128 LDS read, fp32 accumulate
__device__ __forceinline__ void h8fma(float t, uint4 hv, float acc[8]) {
    float2 p01 = __half22float2(*(const __half2*)&hv.x);
    float2 p23 = __half22float2(*(const __half2*)&hv.y);
    float2 p45 = __half22float2(*(const __half2*)&hv.z);
    float2 p67 = __half22float2(*(const __half2*)&hv.w);
    acc[0] = fmaf(t, p01.x, acc[0]); acc[1] = fmaf(t, p01.y, acc[1]);
    acc[2] = fmaf(t, p23.x, acc[2]); acc[3] = fmaf(t, p23.y, acc[3]);
    acc[4] = fmaf(t, p45.x, acc[4]); acc[5] = fmaf(t, p45.y, acc[5]);
    acc[6] = fmaf(t, p67.x, acc[6]); acc[7] = fmaf(t, p67.y, acc[7]);
}

// ---------------- tables: 1D taps + boundary sums ----------------
__global__ void tables_kernel(const float* __restrict__ sigma2,
                              const float* __restrict__ sigma3,
                              float* __restrict__ taps2, float* __restrict__ taps3,
                              float* __restrict__ B2, float* __restrict__ B3)
{
    int t = threadIdx.x;
    if (t < 2 * NC) {
        int c = t % NC;
        const float* sig = (t < NC) ? sigma2 : sigma3;
        float* taps = (t < NC) ? taps2 : taps3;
        float sv = sig[c];
        float s2 = sv * sv;
        float w[K];
        float sum = 0.f;
        for (int j = 0; j < K; j++) {
            float d = (float)(j - HSR);
            w[j] = expf(-d * d / (2.f * s2));
            sum += w[j];
        }
        float inv = 1.f / sum;   // sum3d = sum^3; per-axis norm by sum reproduces it
        for (int j = 0; j < K; j++) taps[c * K + j] = w[j] * inv;
    }
    __syncthreads();
    for (int i = t; i < NC * 96; i += blockDim.x) {
        int c = i / 96, p = i % 96;
        float s2v = 0.f, s3v = 0.f;
        for (int j = 0; j < K; j++) {
            int q = p + j - HSR;
            if (q >= 0 && q < 96) { s2v += taps2[c * K + j]; s3v += taps3[c * K + j]; }
        }
        B2[i] = s2v;
        B3[i] = s3v;
    }
}

// ---------------- softmax over C (float4); applies 1/eta ------
__global__ __launch_bounds__(256) void softmax_kernel(const float* __restrict__ a,
                                                      const float* __restrict__ eta,
                                                      float* __restrict__ u)
{
    int i = blockIdx.x * 256 + threadIdx.x;
    const float4* A = (const float4*)a;
    float4* U = (float4*)u;
    float inv_eta = 1.f / eta[0];
    float4 a0 = A[i], a1 = A[i + VOL4], a2 = A[i + 2 * VOL4], a3 = A[i + 3 * VOL4];
#define SM_COMP(f)                                                              \
    {                                                                           \
        float b0 = a0.f * inv_eta, b1 = a1.f * inv_eta;                         \
        float b2 = a2.f * inv_eta, b3 = a3.f * inv_eta;                         \
        float m = fmaxf(fmaxf(b0, b1), fmaxf(b2, b3));                          \
        float e0 = __expf(b0 - m), e1 = __expf(b1 - m);                         \
        float e2 = __expf(b2 - m), e3 = __expf(b3 - m);                         \
        float inv = 1.f / (e0 + e1 + e2 + e3);                                  \
        a0.f = e0 * inv; a1.f = e1 * inv; a2.f = e2 * inv; a3.f = e3 * inv;     \
    }
    SM_COMP(x) SM_COMP(y) SM_COMP(z) SM_COMP(w)
    U[i] = a0; U[i + VOL4] = a1; U[i + 2 * VOL4] = a2; U[i + 3 * VOL4] = a3;
}

// ---------------- K1: z-conv of {u*I, u (ker_lif), u (ker)} -> fp16 outs -----
__global__ __launch_bounds__(256) void pass1_z(const float* __restrict__ u,
                                               const float* __restrict__ I,
                                               const float* __restrict__ taps2,
                                               const float* __restrict__ taps3,
                                               __half* __restrict__ a0, __half* __restrict__ a1,
                                               __half* __restrict__ a2)
{
    int p4 = blockIdx.x * 256 + threadIdx.x;   // 4-value index within plane
    int s  = blockIdx.y;
    int c  = blockIdx.z;
    int z0 = s * SEGZ;
    const float4* ub = (const float4*)(u + (size_t)c * VOL) + p4;
    const float4* Ib = (const float4*)I + p4;
    float t3[K], t2[K];
#pragma unroll
    for (int j = 0; j < K; j++) { t3[j] = taps3[c * K + j]; t2[j] = taps2[c * K + j]; }
    float4 wu[K], wui[K];
#pragma unroll
    for (int j = 0; j < K - 1; j++) {
        int z = z0 + j - HSR;
        float4 uv = f4zero(), iv = f4zero();
        if (z >= 0 && z < 96) { uv = ub[z * PLANE4]; iv = Ib[z * PLANE4]; }
        wu[j] = uv; wui[j] = f4mul(uv, iv);
    }
    ushort4* o0 = (ushort4*)(a0 + (size_t)c * VOL) + p4;
    ushort4* o1 = (ushort4*)(a1 + (size_t)c * VOL) + p4;
    ushort4* o2 = (ushort4*)(a2 + (size_t)c * VOL) + p4;
    for (int k = 0; k < SEGZ; k++) {
        int z = z0 + k, zl = z + HSR;
        float4 uv = f4zero(), iv = f4zero();
        if (zl < 96) { uv = ub[zl * PLANE4]; iv = Ib[zl * PLANE4]; }
        wu[K - 1] = uv; wui[K - 1] = f4mul(uv, iv);
        float4 s0 = f4zero(), s1 = f4zero(), s2 = f4zero();
#pragma unroll
        for (int j = 0; j < K; j++) {
            s0 = f4fma(t3[j], wui[j], s0);
            s1 = f4fma(t3[j], wu[j], s1);
            s2 = f4fma(t2[j], wu[j], s2);
        }
        o0[z * PLANE4] = f4toh4(s0);
        o1[z * PLANE4] = f4toh4(s1);
        o2[z * PLANE4] = f4toh4(s2);
#pragma unroll
        for (int j = 0; j < K - 1; j++) { wu[j] = wu[j + 1]; wui[j] = wui[j + 1]; }
    }
}

// ---------------- K2: fused y+x conv of 3 fp16 fields -> Cn, q (fp16) --------
// fp16 lin in LDS (pure copy load), fp32 mid. LDS 35.5 KB -> 4 blocks/CU.
__global__ __launch_bounds__(TPBYX) void pass2_yx(const __half* __restrict__ a0,
                                                  const __half* __restrict__ a1,
                                                  const __half* __restrict__ a2,
                                                  const float* __restrict__ taps2,
                                                  const float* __restrict__ taps3,
                                                  const float* __restrict__ B2,
                                                  __half* __restrict__ Cn,
                                                  __half* __restrict__ q)
{
    __shared__ __half linh[3][YTH * LINWH];
    __shared__ float  mid[3][YT * MIDW];
    int yt = blockIdx.x, z = blockIdx.y, c = blockIdx.z;
    int y0 = yt * YT, tid = threadIdx.x;
    size_t base = (size_t)c * VOL + (size_t)z * PLANE;
    {
        const ushort4* g0 = (const ushort4*)(a0 + base);
        const ushort4* g1 = (const ushort4*)(a1 + base);
        const ushort4* g2 = (const ushort4*)(a2 + base);
        const ushort4 zz = make_ushort4(0, 0, 0, 0);
#pragma unroll
        for (int i4 = tid; i4 < NF4; i4 += TPBYX) {
            int r = i4 / 24, k = i4 - r * 24;
            int gy = y0 - HSR + r;
            bool ok = (gy >= 0 && gy < 96);
            int gi = gy * 24 + k;
            int li = r * LINWH + 8 + k * 4;
            *(ushort4*)&linh[0][li] = ok ? g0[gi] : zz;
            *(ushort4*)&linh[1][li] = ok ? g1[gi] : zz;
            *(ushort4*)&linh[2][li] = ok ? g2[gi] : zz;
        }
    }
    if (tid < YTH * 4) {   // zero lin x-pads: 4 ushort4 per row (2 left, 2 right)
        int r = tid >> 2, p = tid & 3;
        int idx = r * LINWH + (p < 2 ? 4 * p : 104 + 4 * (p - 2));
        const ushort4 zz = make_ushort4(0, 0, 0, 0);
        *(ushort4*)&linh[0][idx] = zz;
        *(ushort4*)&linh[1][idx] = zz;
        *(ushort4*)&linh[2][idx] = zz;
    }
    if (tid < 128) {   // zero mid x-pads
        int r = tid >> 3, p = tid & 7;
        int idx = r * MIDW + (p < 4 ? p : 96 + p);
        mid[0][idx] = 0.f; mid[1][idx] = 0.f; mid[2][idx] = 0.f;
    }
    float t3[K], t2[K];
#pragma unroll
    for (int j = 0; j < K; j++) { t3[j] = taps3[c * K + j]; t2[j] = taps2[c * K + j]; }
    __syncthreads();
    int r  = tid / 12;
    int xb = (tid - r * 12) * 8;
    // ---- y-conv: one b128 (8 halves) per tap per field; fp32 accumulate ----
#pragma unroll
    for (int f = 0; f < 3; f++) {
        const float* tp = (f < 2) ? t3 : t2;
        float acc[8];
#pragma unroll
        for (int i = 0; i < 8; i++) acc[i] = 0.f;
#pragma unroll
        for (int j = 0; j < K; j++) {
            uint4 hv = *(const uint4*)&linh[f][(r + j) * LINWH + 8 + xb];
            h8fma(tp[j], hv, acc);
        }
        float4* mp = (float4*)&mid[f][r * MIDW + 4 + xb];
        mp[0] = *(float4*)&acc[0];
        mp[1] = *(float4*)&acc[4];
    }
    __syncthreads();
    // ---- x-conv from fp32 mid (aligned b128 window) ----
    float outA[8], outB[8], outC[8];
    {
        float wf[16];
#pragma unroll
        for (int f = 0; f < 3; f++) {
            const float* tp = (f < 2) ? t3 : t2;
            const float4* wp = (const float4*)&mid[f][r * MIDW + xb];
            *(float4*)&wf[0]  = wp[0];
            *(float4*)&wf[4]  = wp[1];
            *(float4*)&wf[8]  = wp[2];
            *(float4*)&wf[12] = wp[3];
            float* dst = (f == 0) ? outA : (f == 1) ? outB : outC;
#pragma unroll
            for (int k = 0; k < 8; k++) {
                float s = 0.f;
#pragma unroll
                for (int j = 0; j < K; j++) s = fmaf(tp[j], wf[k + j + 1], s);
                dst[k] = s;
            }
        }
    }
    int y = y0 + r;
    float Bz = B2[c * 96 + z];
    float By = B2[c * 96 + y];
    float Bx[8];
    {
        const float4* bx = (const float4*)&B2[c * 96 + xb];
        *(float4*)&Bx[0] = bx[0];
        *(float4*)&Bx[4] = bx[1];
    }
    float co[8], qo[8];
#pragma unroll
    for (int k = 0; k < 8; k++) {
        co[k] = (outA[k] + 1e-6f) / (outB[k] + 1e-6f);
        qo[k] = fmaf(Bz * By, Bx[k], -2.f * outC[k]);
    }
    ushort4* cp = (ushort4*)(Cn + base + y * 96 + xb);
    ushort4* qp = (ushort4*)(q  + base + y * 96 + xb);
    cp[0] = f4toh4(*(float4*)&co[0]);
    cp[1] = f4toh4(*(float4*)&co[4]);
    qp[0] = f4toh4(*(float4*)&qo[0]);
    qp[1] = f4toh4(*(float4*)&qo[4]);
}

// ---------------- K3: z-conv of {Cn, Cn^2}, fp16 in/out ----------------
__global__ __launch_bounds__(256) void pass4_z(const __half* __restrict__ Cn,
                                               const float* __restrict__ taps3,
                                               __half* __restrict__ b0, __half* __restrict__ b1)
{
    int p4 = blockIdx.x * 256 + threadIdx.x;
    int s  = blockIdx.y;
    int c  = blockIdx.z;
    int z0 = s * SEGZ;
    const ushort4* ib = (const ushort4*)(Cn + (size_t)c * VOL) + p4;
    float t3[K];
#pragma unroll
    for (int j = 0; j < K; j++) t3[j] = taps3[c * K + j];
    float4 w[K];
#pragma unroll
    for (int j = 0; j < K - 1; j++) {
        int z = z0 + j - HSR;
        float4 v = f4zero();
        if (z >= 0 && z < 96) v = h4tof4(ib[z * PLANE4]);
        w[j] = v;
    }
    ushort4* o0 = (ushort4*)(b0 + (size_t)c * VOL) + p4;
    ushort4* o1 = (ushort4*)(b1 + (size_t)c * VOL) + p4;
    for (int k = 0; k < SEGZ; k++) {
        int z = z0 + k, zl = z + HSR;
        float4 v = f4zero();
        if (zl < 96) v = h4tof4(ib[zl * PLANE4]);
        w[K - 1] = v;
        float4 s0 = f4zero(), s1 = f4zero();
#pragma unroll
        for (int j = 0; j < K; j++) {
            s0 = f4fma(t3[j], w[j], s0);
            s1 = f4fmasq(t3[j], w[j], s1);
        }
        o0[z * PLANE4] = f4toh4(s0);
        o1[z * PLANE4] = f4toh4(s1);
#pragma unroll
        for (int j = 0; j < K - 1; j++) w[j] = w[j + 1];
    }
}

// ---------------- K4: fused y+x conv of {c0,c1} (fp16) + Lif + arg (fp32) ----
// fp16 lin, fp32 mid. LDS 23.7 KB -> 6 blocks/CU.
__global__ __launch_bounds__(TPBYX) void pass5_yx(const __half* __restrict__ cz0,
                                                  const __half* __restrict__ cz1,
                                                  const __half* __restrict__ q,
                                                  const float* __restrict__ o,
                                                  const float* __restrict__ I,
                                                  const float* __restrict__ taps3,
                                                  const float* __restrict__ B3,
                                                  const float* __restrict__ lam,
                                                  const float* __restrict__ mu,
                                                  float* __restrict__ argb)
{
    __shared__ __half linh[2][YTH * LINWH];
    __shared__ float  mid[2][YT * MIDW];
    int yt = blockIdx.x, z = blockIdx.y, c = blockIdx.z;
    int y0 = yt * YT, tid = threadIdx.x;
    size_t base = (size_t)c * VOL + (size_t)z * PLANE;
    {
        const ushort4* g0 = (const ushort4*)(cz0 + base);
        const ushort4* g1 = (const ushort4*)(cz1 + base);
        const ushort4 zz = make_ushort4(0, 0, 0, 0);
#pragma unroll
        for (int i4 = tid; i4 < NF4; i4 += TPBYX) {
            int r = i4 / 24, k = i4 - r * 24;
            int gy = y0 - HSR + r;
            bool ok = (gy >= 0 && gy < 96);
            int gi = gy * 24 + k;
            int li = r * LINWH + 8 + k * 4;
            *(ushort4*)&linh[0][li] = ok ? g0[gi] : zz;
            *(ushort4*)&linh[1][li] = ok ? g1[gi] : zz;
        }
    }
    if (tid < YTH * 4) {
        int r = tid >> 2, p = tid & 3;
        int idx = r * LINWH + (p < 2 ? 4 * p : 104 + 4 * (p - 2));
        const ushort4 zz = make_ushort4(0, 0, 0, 0);
        *(ushort4*)&linh[0][idx] = zz;
        *(ushort4*)&linh[1][idx] = zz;
    }
    if (tid < 128) {
        int r = tid >> 3, p = tid & 7;
        int idx = r * MIDW + (p < 4 ? p : 96 + p);
        mid[0][idx] = 0.f; mid[1][idx] = 0.f;
    }
    float t3[K];
#pragma unroll
    for (int j = 0; j < K; j++) t3[j] = taps3[c * K + j];
    __syncthreads();
    int r  = tid / 12;
    int xb = (tid - r * 12) * 8;
#pragma unroll
    for (int f = 0; f < 2; f++) {
        float acc[8];
#pragma unroll
        for (int i = 0; i < 8; i++) acc[i] = 0.f;
#pragma unroll
        for (int j = 0; j < K; j++) {
            uint4 hv = *(const uint4*)&linh[f][(r + j) * LINWH + 8 + xb];
            h8fma(t3[j], hv, acc);
        }
        float4* mp = (float4*)&mid[f][r * MIDW + 4 + xb];
        mp[0] = *(float4*)&acc[0];
        mp[1] = *(float4*)&acc[4];
    }
    __syncthreads();
    float d0[8], d1[8];
    {
        float wf[16];
#pragma unroll
        for (int f = 0; f < 2; f++) {
            const float4* wp = (const float4*)&mid[f][r * MIDW + xb];
            *(float4*)&wf[0]  = wp[0];
            *(float4*)&wf[4]  = wp[1];
            *(float4*)&wf[8]  = wp[2];
            *(float4*)&wf[12] = wp[3];
            float* dst = (f == 0) ? d0 : d1;
#pragma unroll
            for (int k = 0; k < 8; k++) {
                float s = 0.f;
#pragma unroll
                for (int j = 0; j < K; j++) s = fmaf(t3[j], wf[k + j + 1], s);
                dst[k] = s;
            }
        }
    }
    int y = y0 + r;
    int v = z * PLANE + y * 96 + xb;
    float lamv = lam[0], muv = mu[0];
    float Bz = B3[c * 96 + z];
    float By = B3[c * 96 + y];
    float Bx[8], Ivv[8], ov[8], qv[8];
    {
        const float4* bx = (const float4*)&B3[c * 96 + xb];
        *(float4*)&Bx[0] = bx[0]; *(float4*)&Bx[4] = bx[1];
        const float4* ip = (const float4*)&I[v];
        *(float4*)&Ivv[0] = ip[0]; *(float4*)&Ivv[4] = ip[1];
        const float4* op = (const float4*)&o[(size_t)c * VOL + v];
        *(float4*)&ov[0] = op[0]; *(float4*)&ov[4] = op[1];
        const ushort4* qp = (const ushort4*)(q + (size_t)c * VOL + v);
        *(float4*)&qv[0] = h4tof4(qp[0]);
        *(float4*)&qv[4] = h4tof4(qp[1]);
    }
    float res[8];
#pragma unroll
    for (int k = 0; k < 8; k++) {
        float Iv = Ivv[k];
        float cones = Bz * By * Bx[k];
        float Lif = d1[k] - 2.f * Iv * d0[k] + Iv * Iv * cones;
        res[k] = ov[k] - muv * Lif - lamv * qv[k];   // unscaled; softmax applies 1/eta
    }
    float* ap = argb + base + y * 96 + xb;
    *(float4*)ap       = *(float4*)&res[0];
    *(float4*)(ap + 4) = *(float4*)&res[4];
}

extern "C" void kernel_launch(void* const* d_in, const int* in_sizes, int n_in,
                              void* d_out, int out_size, void* d_ws, size_t ws_size,
                              hipStream_t stream)
{
    const float* o      = (const float*)d_in[0];
    const float* I      = (const float*)d_in[1];
    const float* sigma2 = (const float*)d_in[2];
    const float* sigma3 = (const float*)d_in[3];
    const float* eta    = (const float*)d_in[4];
    const float* lam    = (const float*)d_in[5];
    const float* mu     = (const float*)d_in[6];
    float* u = (float*)d_out;

    float* wsf = (float*)d_ws;
    float* taps2 = wsf;              // 28 floats
    float* taps3 = wsf + 32;
    float* B2    = wsf + 64;         // 384 floats
    float* B3    = wsf + 64 + NC * 96;
    const size_t VCs = (size_t)NC * VOL;
    float* argb  = wsf + 1024;       // fp32 arg buffer (4*VOL floats)
    __half* hbuf = (__half*)(wsf + 1024 + VCs);
    __half* a0 = hbuf;               // z-conv outs (fp16)
    __half* a1 = hbuf + VCs;
    __half* a2 = hbuf + 2 * VCs;
    __half* Cn = hbuf + 3 * VCs;
    __half* qb = hbuf + 4 * VCs;
    __half* c0 = hbuf + 5 * VCs;     // z-conv of Cn, Cn^2 (fp16)
    __half* c1 = hbuf + 6 * VCs;

    const dim3 gridZ(PLANE4 / 256, NSEGZ, NC);  // 9 x 12 x 4 = 432 blocks (256t)
    const dim3 gridYX(96 / YT, 96, NC);         // 6 x 96 x 4 = 2304 blocks (192t)
    const int gridV4 = VOL4 / 256;              // 864

    tables_kernel<<<1, 512, 0, stream>>>(sigma2, sigma3, taps2, taps3, B2, B3);
    softmax_kernel<<<gridV4, 256, 0, stream>>>(o, eta, u);   // u0 = softmax(o/eta)
    for (int it = 0; it < 10; it++) {
        pass1_z<<<gridZ, 256, 0, stream>>>(u, I, taps2, taps3, a0, a1, a2);
        pass2_yx<<<gridYX, TPBYX, 0, stream>>>(a0, a1, a2, taps2, taps3, B2, Cn, qb);
        pass4_z<<<gridZ, 256, 0, stream>>>(Cn, taps3, c0, c1);
        pass5_yx<<<gridYX, TPBYX, 0, stream>>>(c0, c1, qb, o, I, taps3, B3,
                                               lam, mu, argb);
        softmax_kernel<<<gridV4, 256, 0, stream>>>(argb, eta, u);
    }
}